// Round 5
// baseline (222.602 us; speedup 1.0000x reference)
//
#include <hip/hip_runtime.h>
#include <cstdint>

#define NSEQ 2048
#define DIM  768
#define NH   12
#define HD   64

typedef __attribute__((ext_vector_type(8)))  short bf16x8;
typedef __attribute__((ext_vector_type(4)))  float f32x4;
typedef __attribute__((ext_vector_type(16))) float f32x16;
typedef __attribute__((ext_vector_type(4)))  int   i32x4;
typedef unsigned short u16;

#define MFMA16(a,b,c) __builtin_amdgcn_mfma_f32_16x16x32_bf16(a,b,c,0,0,0)
#define MFMA32(a,b,c) __builtin_amdgcn_mfma_f32_32x32x16_bf16(a,b,c,0,0,0)

// q' = q * HEAD_DIM^-0.5 * log2(e)  -> attention uses exp2 directly
#define QSCALE 0.1803368801111204f

__device__ __forceinline__ u16 f2bf(float f){
  unsigned u = __builtin_bit_cast(unsigned, f);
  return (u16)((u + 0x7fffu + ((u >> 16) & 1u)) >> 16);   // RNE
}
// pack two floats to bf16x2 in ONE inst (RNE) — T12 recipe (no builtin)
__device__ __forceinline__ int cvtpk(float a, float b){
  int r;
  asm("v_cvt_pk_bf16_f32 %0, %1, %2" : "=v"(r) : "v"(a), "v"(b));
  return r;
}

typedef __attribute__((address_space(1))) void gvoid_t;
typedef __attribute__((address_space(3))) void lvoid_t;
__device__ __forceinline__ void g2l16(const void* g, void* l){
  __builtin_amdgcn_global_load_lds((gvoid_t*)g, (lvoid_t*)l, 16, 0, 0);
}

// ---------------------------------------------------------------------------
// Kernel 0: fp32 -> bf16 conversion of x and the three weight matrices.
// ---------------------------------------------------------------------------
__global__ __launch_bounds__(256) void convert_all(
    const float* __restrict__ x,  const float* __restrict__ wq,
    const float* __restrict__ wk, const float* __restrict__ wv,
    u16* __restrict__ xb, u16* __restrict__ wb){
  int blk = blockIdx.x, tid = threadIdx.x;
  const float* src; u16* dst; long idx;
  if (blk < 6144){ src = x; dst = xb; idx = (long)blk*256 + tid; }
  else {
    int r = blk - 6144; int s = r / 576; r -= s*576;
    src = (s==0) ? wq : (s==1) ? wk : wv;
    dst = wb + (long)s * (768*768);
    idx = (long)r*256 + tid;
  }
  float4 v = ((const float4*)src)[idx];
  ushort4 o;
  o.x = f2bf(v.x); o.y = f2bf(v.y); o.z = f2bf(v.z); o.w = f2bf(v.w);
  ((ushort4*)dst)[idx] = o;
}

// ---------------------------------------------------------------------------
// Kernel 1: fused QKV projection GEMM — EXACT R5 version (measured-good).
// 128x128 tile, BK=64, global_load_lds(16B) + XOR-8 swizzle, 16x16x32 bf16
// MFMA (single operand order, no branch in K-loop), XCD-local bm clustering.
// Outputs: Q (pre-scaled by 0.125*log2e), K as [bh][n][64]; V^T [bh][64][n].
// ---------------------------------------------------------------------------
__global__ __launch_bounds__(256,3) void qkv_gemm(
    const u16* __restrict__ xb, const u16* __restrict__ wb,
    const float* __restrict__ bq, const float* __restrict__ bk,
    const float* __restrict__ bv,
    u16* __restrict__ Qo, u16* __restrict__ Ko, u16* __restrict__ Vo){
  __shared__ __align__(16) u16 ldsX[128*64];
  __shared__ __align__(16) u16 ldsW[128*64];
  int tid  = threadIdx.x;
  int w    = tid >> 6, lane = tid & 63;
  int xcd  = blockIdx.x & 7, j = blockIdx.x >> 3;     // j in [0,144)
  int bm   = xcd*8 + j/18, bn = j%18;
  int wm   = w >> 1, wn = w & 1;
  int l15  = lane & 15, g = lane >> 4;
  int srow = lane >> 3;
  int scol = ((lane & 7) ^ srow) * 8;

  const u16* xg = xb + (long)bm*128*768;
  const u16* wg = wb + (long)bn*128*768;

  f32x4 acc[4][4] = {};

  for (int k0 = 0; k0 < 768; k0 += 64){
    if (k0) __syncthreads();
    #pragma unroll
    for (int jj = 0; jj < 4; jj++){
      int rr = (w*4 + jj)*8 + srow;
      g2l16(xg + (long)rr*768 + k0 + scol, &ldsX[(w*4 + jj)*512]);
      g2l16(wg + (long)rr*768 + k0 + scol, &ldsW[(w*4 + jj)*512]);
    }
    __syncthreads();
    #pragma unroll
    for (int ks = 0; ks < 2; ks++){
      bf16x8 af[4], bfr[4];
      #pragma unroll
      for (int im = 0; im < 4; im++){
        int row = wm*64 + im*16 + l15;
        af[im] = *(const bf16x8*)&ldsX[row*64 + (((ks*4 + g) ^ (row & 7))*8)];
      }
      #pragma unroll
      for (int in = 0; in < 4; in++){
        int row = wn*64 + in*16 + l15;
        bfr[in] = *(const bf16x8*)&ldsW[row*64 + (((ks*4 + g) ^ (row & 7))*8)];
      }
      #pragma unroll
      for (int im = 0; im < 4; im++)
        #pragma unroll
        for (int in = 0; in < 4; in++)
          acc[im][in] = MFMA16(af[im], bfr[in], acc[im][in]);
    }
  }

  int seg = bn / 6;
  const float* bias = (seg==0) ? bq : (seg==1) ? bk : bv;
  #pragma unroll
  for (int in = 0; in < 4; in++){
    int o  = bn*128 + wn*64 + in*16 + l15;
    int oo = o - seg*768;
    int h  = oo >> 6, d = oo & 63;
    float bb = bias[oo];
    #pragma unroll
    for (int im = 0; im < 4; im++){
      int t  = bm*128 + wm*64 + im*16 + g*4;
      int bi = t >> 11, n0 = t & 2047;
      f32x4 a = acc[im][in];
      if (seg == 2){
        ushort4 pk;
        pk.x = f2bf(a[0] + bb); pk.y = f2bf(a[1] + bb);
        pk.z = f2bf(a[2] + bb); pk.w = f2bf(a[3] + bb);
        *(ushort4*)&Vo[((long)(bi*NH + h)*HD + d)*NSEQ + n0] = pk;   // V^T
      } else if (seg == 0){
        #pragma unroll
        for (int r = 0; r < 4; r++)
          Qo[((long)(bi*NH + h)*NSEQ + n0 + r)*HD + d] = f2bf((a[r] + bb)*QSCALE);
      } else {
        #pragma unroll
        for (int r = 0; r < 4; r++)
          Ko[((long)(bi*NH + h)*NSEQ + n0 + r)*HD + d] = f2bf(a[r] + bb);
      }
    }
  }
}

// ---------------------------------------------------------------------------
// Kernel 2: flash attention fwd, 32x32-MFMA pipeline.
// R1: T12 cvt_pk+permlane32_swap + T5 setprio (81.6->72.0us, matched pred).
// R2: counted-vmcnt barriers — NEUTRAL (TLP already hid drain). Kept.
// R3: QKT/SMPV split — FAILED correctness (absmax 0.145) despite identical
//     algebra; unlocalized sched/miscompile-class failure. REVERTED to the
//     R2-proven fused-KH structure.
// R4 change (counter-driven): LDS data pipe was the most-loaded (~57% of
// wall; half of it V-fragment ds_reads). K+V per head = 512KB << 4MB
// per-XCD L2, blocks XCD-pinned -> V staging is Common-mistake #7 overhead.
// V^T fragments are 16 CONTIGUOUS bytes in global; load them directly
// (L2-hit) at the top of each KH window — no vls, no V in STAGE (2 g2l16/
// wave/iter now -> leading vmcnt(2)). vmcnt FIFO audit: vf(i-1) consumption
// by PV forces all older loads (incl K(i)) complete, so vmcnt(2)+barrier
// remains correct.
// ---------------------------------------------------------------------------
__global__ __launch_bounds__(256,3) void attn(
    const u16* __restrict__ Q, const u16* __restrict__ K,
    const u16* __restrict__ VT, float* __restrict__ out){
  __shared__ __align__(16) u16 kls[2][64*64];   // [key][d]   8KB per buf
  int tid = threadIdx.x;
  int w   = tid >> 6, lane = tid & 63;
  int xcd = blockIdx.x & 7, j = blockIdx.x >> 3;   // j in [0,96)
  int bh  = xcd*6 + (j >> 4), qc = j & 15;
  int b   = bh / NH, h = bh - b*NH;
  int l31 = lane & 31, hi = lane >> 5;
  int srow = lane >> 3;
  int scol = ((lane & 7) ^ srow) * 8;

  const u16* Qb = Q  + (long)bh*NSEQ*HD;
  const u16* Kb = K  + (long)bh*NSEQ*HD;
  const u16* Vb = VT + (long)bh*HD*NSEQ;

  int r0 = qc*128 + w*32;
  // Q fragments (B-operand of 32x32x16: k=hi*8+j within 16-d window dk)
  bf16x8 qf[4];
  {
    const u16* qrow = Qb + (long)(r0 + l31)*HD;
    #pragma unroll
    for (int dk = 0; dk < 4; dk++)
      qf[dk] = *(const bf16x8*)&qrow[dk*16 + hi*8];
  }

  // per-lane V^T row bases: d = l31 and d = 32 + l31
  const u16* Vr0 = Vb + (long)l31*NSEQ;
  const u16* Vr1 = Vr0 + 32l*NSEQ;

  f32x16 oa[2] = {};            // O^T [d-tile of 32][r=32]
  float ls = 0.f;               // lane-local row sum (q-row = l31)

#define STAGE(c0, bf)                                                         \
  {                                                                           \
    _Pragma("unroll")                                                         \
    for (int jj = 0; jj < 2; jj++){                                           \
      int rr = jj*32 + w*8;                                                   \
      g2l16(Kb + (long)((c0) + rr + srow)*HD + scol,  &kls[bf][rr*64]);       \
    }                                                                         \
  }

  // one 32-key window: Sᵀ = K·Qᵀ -> exp2 -> cvt_pk/permlane exchange -> PV.
  // V fragments loaded DIRECT from global (L2-resident), issued up-front so
  // ~200cy L2 latency hides under the QK-MFMA + exp2 chain.
#define KH(bf, kh, c0)                                                        \
  {                                                                           \
    bf16x8 vf00 = *(const bf16x8*)&Vr0[(c0) + ((kh)*4 + 0 + hi)*8];           \
    bf16x8 vf01 = *(const bf16x8*)&Vr1[(c0) + ((kh)*4 + 0 + hi)*8];           \
    bf16x8 vf10 = *(const bf16x8*)&Vr0[(c0) + ((kh)*4 + 2 + hi)*8];           \
    bf16x8 vf11 = *(const bf16x8*)&Vr1[(c0) + ((kh)*4 + 2 + hi)*8];           \
    bf16x8 kf[4];                                                             \
    _Pragma("unroll")                                                         \
    for (int dk = 0; dk < 4; dk++)                                            \
      kf[dk] = *(const bf16x8*)                                               \
        &kls[bf][((kh)*32 + l31)*64 + (((dk*2 + hi) ^ (l31 & 7))*8)];         \
    f32x16 T = {};                                                            \
    __builtin_amdgcn_s_setprio(1);                                            \
    _Pragma("unroll")                                                         \
    for (int dk = 0; dk < 4; dk++)                                            \
      T = MFMA32(kf[dk], qf[dk], T);                                          \
    __builtin_amdgcn_s_setprio(0);                                            \
    int PD[4][2];                                                             \
    _Pragma("unroll")                                                         \
    for (int q = 0; q < 4; q++){                                              \
      float p0 = __builtin_amdgcn_exp2f(T[q*4+0]);                            \
      float p1 = __builtin_amdgcn_exp2f(T[q*4+1]);                            \
      float p2 = __builtin_amdgcn_exp2f(T[q*4+2]);                            \
      float p3 = __builtin_amdgcn_exp2f(T[q*4+3]);                            \
      ls += (p0 + p1) + (p2 + p3);                                            \
      PD[q][0] = cvtpk(p0, p1);                                               \
      PD[q][1] = cvtpk(p2, p3);                                               \
    }                                                                         \
    _Pragma("unroll")                                                         \
    for (int kc = 0; kc < 2; kc++){                                           \
      int a0 = PD[2*kc][0], b0 = PD[2*kc+1][0];                               \
      int a1 = PD[2*kc][1], b1 = PD[2*kc+1][1];                               \
      asm("v_permlane32_swap_b32 %0, %1" : "+v"(a0), "+v"(b0));               \
      asm("v_permlane32_swap_b32 %0, %1" : "+v"(a1), "+v"(b1));               \
      i32x4 pr;                                                               \
      pr[0] = a0; pr[1] = a1; pr[2] = b0; pr[3] = b1;                         \
      bf16x8 pf = __builtin_bit_cast(bf16x8, pr);                             \
      bf16x8 vfa = (kc == 0) ? vf00 : vf10;                                   \
      bf16x8 vfb = (kc == 0) ? vf01 : vf11;                                   \
      __builtin_amdgcn_s_setprio(1);                                          \
      oa[0] = MFMA32(vfa, pf, oa[0]);                                         \
      oa[1] = MFMA32(vfb, pf, oa[1]);                                         \
      __builtin_amdgcn_s_setprio(0);                                          \
    }                                                                         \
  }

  STAGE(0, 0);
  __syncthreads();
  for (int i = 0; i < 32; i++){
    int cb = i & 1, nb = cb ^ 1;
    int c0 = i*64;
    STAGE(((i+1) & 31)*64, nb);       // wraps to tile 0 on last iter (safe)
    // leading barrier: prev-iter's 2 K-loads (tile i, buf cb) landed,
    // wave-wide; the 2 just-issued (tile i+1, buf nb) stay in flight.
    __builtin_amdgcn_sched_barrier(0);
    asm volatile("s_waitcnt vmcnt(2) lgkmcnt(0)" ::: "memory");
    __builtin_amdgcn_sched_barrier(0);
    __builtin_amdgcn_s_barrier();
    KH(cb, 0, c0);
    KH(cb, 1, c0);
    // trailing barrier: all waves finished READING buf cb before iter i+1
    // issues g2l16 writes into it. ds_reads were consumed pre-MFMA (lgkm).
    __builtin_amdgcn_sched_barrier(0);
    asm volatile("s_waitcnt lgkmcnt(0)" ::: "memory");
    __builtin_amdgcn_sched_barrier(0);
    __builtin_amdgcn_s_barrier();
  }
#undef STAGE
#undef KH

  // finish row sum: partner lane holds the complementary keys of row l31
  ls += __shfl_xor(ls, 32);
  float inv = 1.f / ls;

  // O^T: col=r=l31, row=d=(reg&3)+8*(reg>>2)+4*hi (+32*dt) -> float4 stores
  float* op = &out[(long)(b*NSEQ + r0 + l31)*DIM + h*HD];
  #pragma unroll
  for (int dt = 0; dt < 2; dt++)
    #pragma unroll
    for (int rq = 0; rq < 4; rq++){
      f32x4 v;
      v[0] = oa[dt][rq*4+0]; v[1] = oa[dt][rq*4+1];
      v[2] = oa[dt][rq*4+2]; v[3] = oa[dt][rq*4+3];
      v *= inv;
      *(f32x4*)&op[dt*32 + rq*8 + hi*4] = v;
    }
}

// ---------------------------------------------------------------------------
extern "C" void kernel_launch(void* const* d_in, const int* in_sizes, int n_in,
                              void* d_out, int out_size, void* d_ws, size_t ws_size,
                              hipStream_t stream){
  (void)in_sizes; (void)n_in; (void)out_size; (void)ws_size;
  const float* x  = (const float*)d_in[0];
  const float* wq = (const float*)d_in[1];
  const float* bq = (const float*)d_in[2];
  const float* wk = (const float*)d_in[3];
  const float* bk = (const float*)d_in[4];
  const float* wv = (const float*)d_in[5];
  const float* bv = (const float*)d_in[6];

  char* ws = (char*)d_ws;
  u16* xb = (u16*)ws;                       // [8192][768]
  u16* wb = (u16*)(ws + 12582912);          // [2304][768]
  u16* Qp = (u16*)(ws + 16121856);          // [48][2048][64]
  u16* Kp = (u16*)(ws + 28704768);          // [48][2048][64]
  u16* Vp = (u16*)(ws + 41287680);          // [48][64][2048]  (V^T)

  convert_all<<<7872, 256, 0, stream>>>(x, wq, wk, wv, xb, wb);
  qkv_gemm<<<1152, 256, 0, stream>>>(xb, wb, bq, bk, bv, Qp, Kp, Vp);
  attn<<<768, 256, 0, stream>>>(Qp, Kp, Vp, (float*)d_out);
}

// Round 6
// 202.701 us; speedup vs baseline: 1.0982x; 1.0982x over previous
//
#include <hip/hip_runtime.h>
#include <cstdint>

#define NSEQ 2048
#define DIM  768
#define NH   12
#define HD   64

typedef __attribute__((ext_vector_type(8)))  short bf16x8;
typedef __attribute__((ext_vector_type(4)))  float f32x4;
typedef __attribute__((ext_vector_type(16))) float f32x16;
typedef __attribute__((ext_vector_type(4)))  int   i32x4;
typedef unsigned short u16;

#define MFMA16(a,b,c) __builtin_amdgcn_mfma_f32_16x16x32_bf16(a,b,c,0,0,0)
#define MFMA32(a,b,c) __builtin_amdgcn_mfma_f32_32x32x16_bf16(a,b,c,0,0,0)

// q' = q * HEAD_DIM^-0.5 * log2(e)  -> attention uses exp2 directly
#define QSCALE 0.1803368801111204f

__device__ __forceinline__ u16 f2bf(float f){
  unsigned u = __builtin_bit_cast(unsigned, f);
  return (u16)((u + 0x7fffu + ((u >> 16) & 1u)) >> 16);   // RNE
}
// pack two floats to bf16x2 in ONE inst (RNE) — T12 recipe (no builtin)
__device__ __forceinline__ int cvtpk(float a, float b){
  int r;
  asm("v_cvt_pk_bf16_f32 %0, %1, %2" : "=v"(r) : "v"(a), "v"(b));
  return r;
}

typedef __attribute__((address_space(1))) void gvoid_t;
typedef __attribute__((address_space(3))) void lvoid_t;
__device__ __forceinline__ void g2l16(const void* g, void* l){
  __builtin_amdgcn_global_load_lds((gvoid_t*)g, (lvoid_t*)l, 16, 0, 0);
}

// ---------------------------------------------------------------------------
// Kernel 0: fp32 -> bf16 conversion of x and the three weight matrices.
// ---------------------------------------------------------------------------
__global__ __launch_bounds__(256) void convert_all(
    const float* __restrict__ x,  const float* __restrict__ wq,
    const float* __restrict__ wk, const float* __restrict__ wv,
    u16* __restrict__ xb, u16* __restrict__ wb){
  int blk = blockIdx.x, tid = threadIdx.x;
  const float* src; u16* dst; long idx;
  if (blk < 6144){ src = x; dst = xb; idx = (long)blk*256 + tid; }
  else {
    int r = blk - 6144; int s = r / 576; r -= s*576;
    src = (s==0) ? wq : (s==1) ? wk : wv;
    dst = wb + (long)s * (768*768);
    idx = (long)r*256 + tid;
  }
  float4 v = ((const float4*)src)[idx];
  ushort4 o;
  o.x = f2bf(v.x); o.y = f2bf(v.y); o.z = f2bf(v.z); o.w = f2bf(v.w);
  ((ushort4*)dst)[idx] = o;
}

// ---------------------------------------------------------------------------
// Kernel 1: fused QKV projection GEMM — EXACT R5 version (measured-good).
// 128x128 tile, BK=64, global_load_lds(16B) + XOR-8 swizzle, 16x16x32 bf16
// MFMA (single operand order, no branch in K-loop), XCD-local bm clustering.
// Outputs: Q (pre-scaled by 0.125*log2e), K as [bh][n][64]; V^T [bh][64][n].
// ---------------------------------------------------------------------------
__global__ __launch_bounds__(256,3) void qkv_gemm(
    const u16* __restrict__ xb, const u16* __restrict__ wb,
    const float* __restrict__ bq, const float* __restrict__ bk,
    const float* __restrict__ bv,
    u16* __restrict__ Qo, u16* __restrict__ Ko, u16* __restrict__ Vo){
  __shared__ __align__(16) u16 ldsX[128*64];
  __shared__ __align__(16) u16 ldsW[128*64];
  int tid  = threadIdx.x;
  int w    = tid >> 6, lane = tid & 63;
  int xcd  = blockIdx.x & 7, j = blockIdx.x >> 3;     // j in [0,144)
  int bm   = xcd*8 + j/18, bn = j%18;
  int wm   = w >> 1, wn = w & 1;
  int l15  = lane & 15, g = lane >> 4;
  int srow = lane >> 3;
  int scol = ((lane & 7) ^ srow) * 8;

  const u16* xg = xb + (long)bm*128*768;
  const u16* wg = wb + (long)bn*128*768;

  f32x4 acc[4][4] = {};

  for (int k0 = 0; k0 < 768; k0 += 64){
    if (k0) __syncthreads();
    #pragma unroll
    for (int jj = 0; jj < 4; jj++){
      int rr = (w*4 + jj)*8 + srow;
      g2l16(xg + (long)rr*768 + k0 + scol, &ldsX[(w*4 + jj)*512]);
      g2l16(wg + (long)rr*768 + k0 + scol, &ldsW[(w*4 + jj)*512]);
    }
    __syncthreads();
    #pragma unroll
    for (int ks = 0; ks < 2; ks++){
      bf16x8 af[4], bfr[4];
      #pragma unroll
      for (int im = 0; im < 4; im++){
        int row = wm*64 + im*16 + l15;
        af[im] = *(const bf16x8*)&ldsX[row*64 + (((ks*4 + g) ^ (row & 7))*8)];
      }
      #pragma unroll
      for (int in = 0; in < 4; in++){
        int row = wn*64 + in*16 + l15;
        bfr[in] = *(const bf16x8*)&ldsW[row*64 + (((ks*4 + g) ^ (row & 7))*8)];
      }
      #pragma unroll
      for (int im = 0; im < 4; im++)
        #pragma unroll
        for (int in = 0; in < 4; in++)
          acc[im][in] = MFMA16(af[im], bfr[in], acc[im][in]);
    }
  }

  int seg = bn / 6;
  const float* bias = (seg==0) ? bq : (seg==1) ? bk : bv;
  #pragma unroll
  for (int in = 0; in < 4; in++){
    int o  = bn*128 + wn*64 + in*16 + l15;
    int oo = o - seg*768;
    int h  = oo >> 6, d = oo & 63;
    float bb = bias[oo];
    #pragma unroll
    for (int im = 0; im < 4; im++){
      int t  = bm*128 + wm*64 + im*16 + g*4;
      int bi = t >> 11, n0 = t & 2047;
      f32x4 a = acc[im][in];
      if (seg == 2){
        ushort4 pk;
        pk.x = f2bf(a[0] + bb); pk.y = f2bf(a[1] + bb);
        pk.z = f2bf(a[2] + bb); pk.w = f2bf(a[3] + bb);
        *(ushort4*)&Vo[((long)(bi*NH + h)*HD + d)*NSEQ + n0] = pk;   // V^T
      } else if (seg == 0){
        #pragma unroll
        for (int r = 0; r < 4; r++)
          Qo[((long)(bi*NH + h)*NSEQ + n0 + r)*HD + d] = f2bf((a[r] + bb)*QSCALE);
      } else {
        #pragma unroll
        for (int r = 0; r < 4; r++)
          Ko[((long)(bi*NH + h)*NSEQ + n0 + r)*HD + d] = f2bf(a[r] + bb);
      }
    }
  }
}

// ---------------------------------------------------------------------------
// Kernel 2: flash attention fwd, 32x32-MFMA pipeline.
// R1: T12 cvt_pk+permlane32_swap + T5 setprio (81.6->72.0us, matched pred).
// R2: counted-vmcnt barriers — NEUTRAL. Kept.
// R3: QKT/SMPV interleave (two live T) — FAILED correctness. Reverted.
// R4: V direct-from-L2 — REGRESSION +58% (gather: 32 lines/load). Reverted.
// R5 change (counter-driven): LDS pipe is the widest (~57%/iter; 4 extra
// conflict-cyc per b128 read is STRUCTURAL for 32 lanes x 32 rows of 128B
// rows — no swizzle fixes it; g2l16 linear-dest forbids row phase shifts).
// So halve READ COUNT per MFMA: 128-thread blocks, 2 waves, each wave owns
// 64 q-rows (2 q-tiles A/B processed SEQUENTIALLY per window — one T live
// at a time, R2-proven shape). kf/vf fragments read ONCE, feed both
// q-tiles. Grid stays 768 (3 blocks/CU balanced); per-CU MFMA/VALU totals
// unchanged; per-CU LDS reads halve.
// ---------------------------------------------------------------------------
__global__ __launch_bounds__(128,2) void attn(
    const u16* __restrict__ Q, const u16* __restrict__ K,
    const u16* __restrict__ VT, float* __restrict__ out){
  __shared__ __align__(16) u16 kls[2][64*64];   // [key][d]   8KB per buf
  __shared__ __align__(16) u16 vls[2][64*64];   // [d][key]   8KB per buf
  int tid = threadIdx.x;
  int w   = tid >> 6, lane = tid & 63;          // w in {0,1}
  int xcd = blockIdx.x & 7, j = blockIdx.x >> 3;   // j in [0,96)
  int bh  = xcd*6 + (j >> 4), qc = j & 15;
  int b   = bh / NH, h = bh - b*NH;
  int l31 = lane & 31, hi = lane >> 5;
  int srow = lane >> 3;
  int scol = ((lane & 7) ^ srow) * 8;

  const u16* Qb = Q  + (long)bh*NSEQ*HD;
  const u16* Kb = K  + (long)bh*NSEQ*HD;
  const u16* Vb = VT + (long)bh*HD*NSEQ;

  int r0 = qc*128 + w*64;       // wave owns q-rows [r0, r0+64)
  // Q fragments for both q-tiles (B-operand of 32x32x16)
  bf16x8 qfA[4], qfB[4];
  {
    const u16* qa = Qb + (long)(r0 + l31)*HD;
    const u16* qb2 = Qb + (long)(r0 + 32 + l31)*HD;
    #pragma unroll
    for (int dk = 0; dk < 4; dk++){
      qfA[dk] = *(const bf16x8*)&qa[dk*16 + hi*8];
      qfB[dk] = *(const bf16x8*)&qb2[dk*16 + hi*8];
    }
  }

  f32x16 oaA[2] = {}, oaB[2] = {};   // O^T per q-tile
  float lsA = 0.f, lsB = 0.f;

  // 2 waves cover 64 K-rows + 64 V-rows: 4+4 g2l16 per wave
#define STAGE(c0, bf)                                                         \
  {                                                                           \
    _Pragma("unroll")                                                         \
    for (int jj = 0; jj < 4; jj++){                                           \
      int rr = jj*16 + w*8;                                                   \
      g2l16(Kb + (long)((c0) + rr + srow)*HD + scol,  &kls[bf][rr*64]);       \
      g2l16(Vb + (long)(rr + srow)*NSEQ + (c0) + scol, &vls[bf][rr*64]);      \
    }                                                                         \
  }

  // softmax + PV for ONE q-tile (R2-proven shape; kf/vf supplied by caller)
#define SMPV(T, vfs, oa, ls)                                                  \
  {                                                                           \
    int PD[4][2];                                                             \
    _Pragma("unroll")                                                         \
    for (int q = 0; q < 4; q++){                                              \
      float p0 = __builtin_amdgcn_exp2f(T[q*4+0]);                            \
      float p1 = __builtin_amdgcn_exp2f(T[q*4+1]);                            \
      float p2 = __builtin_amdgcn_exp2f(T[q*4+2]);                            \
      float p3 = __builtin_amdgcn_exp2f(T[q*4+3]);                            \
      ls += (p0 + p1) + (p2 + p3);                                            \
      PD[q][0] = cvtpk(p0, p1);                                               \
      PD[q][1] = cvtpk(p2, p3);                                               \
    }                                                                         \
    _Pragma("unroll")                                                         \
    for (int kc = 0; kc < 2; kc++){                                           \
      int a0 = PD[2*kc][0], b0 = PD[2*kc+1][0];                               \
      int a1 = PD[2*kc][1], b1 = PD[2*kc+1][1];                               \
      asm("v_permlane32_swap_b32 %0, %1" : "+v"(a0), "+v"(b0));               \
      asm("v_permlane32_swap_b32 %0, %1" : "+v"(a1), "+v"(b1));               \
      i32x4 pr;                                                               \
      pr[0] = a0; pr[1] = a1; pr[2] = b0; pr[3] = b1;                         \
      bf16x8 pf = __builtin_bit_cast(bf16x8, pr);                             \
      __builtin_amdgcn_s_setprio(1);                                          \
      oa[0] = MFMA32(vfs[kc][0], pf, oa[0]);                                  \
      oa[1] = MFMA32(vfs[kc][1], pf, oa[1]);                                  \
      __builtin_amdgcn_s_setprio(0);                                          \
    }                                                                         \
  }

  // one 32-key window: read kf/vf ONCE, run QK->SM->PV for q-tile A then B
#define KH(bf, kh)                                                            \
  {                                                                           \
    bf16x8 kf[4];                                                             \
    _Pragma("unroll")                                                         \
    for (int dk = 0; dk < 4; dk++)                                            \
      kf[dk] = *(const bf16x8*)                                               \
        &kls[bf][((kh)*32 + l31)*64 + (((dk*2 + hi) ^ (l31 & 7))*8)];         \
    bf16x8 vfs[2][2];                                                         \
    _Pragma("unroll")                                                         \
    for (int kc = 0; kc < 2; kc++)                                            \
      _Pragma("unroll")                                                       \
      for (int dt = 0; dt < 2; dt++)                                          \
        vfs[kc][dt] = *(const bf16x8*)                                        \
          &vls[bf][(dt*32 + l31)*64 + ((((kh)*4 + kc*2 + hi) ^ (l31 & 7))*8)];\
    {                                                                         \
      f32x16 T = {};                                                          \
      __builtin_amdgcn_s_setprio(1);                                          \
      _Pragma("unroll")                                                       \
      for (int dk = 0; dk < 4; dk++)                                          \
        T = MFMA32(kf[dk], qfA[dk], T);                                       \
      __builtin_amdgcn_s_setprio(0);                                          \
      SMPV(T, vfs, oaA, lsA);                                                 \
    }                                                                         \
    {                                                                         \
      f32x16 T = {};                                                          \
      __builtin_amdgcn_s_setprio(1);                                          \
      _Pragma("unroll")                                                       \
      for (int dk = 0; dk < 4; dk++)                                          \
        T = MFMA32(kf[dk], qfB[dk], T);                                       \
      __builtin_amdgcn_s_setprio(0);                                          \
      SMPV(T, vfs, oaB, lsB);                                                 \
    }                                                                         \
  }

  STAGE(0, 0);
  __syncthreads();
  for (int i = 0; i < 32; i++){
    int cb = i & 1, nb = cb ^ 1;
    STAGE(((i+1) & 31)*64, nb);       // wraps to tile 0 on last iter (safe)
    // leading barrier: prev-iter's 8 loads (tile i, buf cb) landed, wave-wide;
    // the 8 just-issued loads (tile i+1, buf nb) stay in flight across it.
    __builtin_amdgcn_sched_barrier(0);
    asm volatile("s_waitcnt vmcnt(8) lgkmcnt(0)" ::: "memory");
    __builtin_amdgcn_sched_barrier(0);
    __builtin_amdgcn_s_barrier();
    KH(cb, 0);
    KH(cb, 1);
    // trailing barrier: all waves finished READING buf cb before iter i+1
    // issues g2l16 writes into it. ds_reads were consumed pre-MFMA (lgkm).
    __builtin_amdgcn_sched_barrier(0);
    asm volatile("s_waitcnt lgkmcnt(0)" ::: "memory");
    __builtin_amdgcn_sched_barrier(0);
    __builtin_amdgcn_s_barrier();
  }
#undef STAGE
#undef KH
#undef SMPV

  // finish row sums: partner lane holds the complementary keys of row l31
  lsA += __shfl_xor(lsA, 32);
  lsB += __shfl_xor(lsB, 32);
  float invA = 1.f / lsA, invB = 1.f / lsB;

  // O^T: col=r=l31, row=d=(reg&3)+8*(reg>>2)+4*hi (+32*dt) -> float4 stores
  float* opA = &out[(long)(b*NSEQ + r0 + l31)*DIM + h*HD];
  float* opB = &out[(long)(b*NSEQ + r0 + 32 + l31)*DIM + h*HD];
  #pragma unroll
  for (int dt = 0; dt < 2; dt++)
    #pragma unroll
    for (int rq = 0; rq < 4; rq++){
      f32x4 v;
      v[0] = oaA[dt][rq*4+0]; v[1] = oaA[dt][rq*4+1];
      v[2] = oaA[dt][rq*4+2]; v[3] = oaA[dt][rq*4+3];
      v *= invA;
      *(f32x4*)&opA[dt*32 + rq*8 + hi*4] = v;
      f32x4 u;
      u[0] = oaB[dt][rq*4+0]; u[1] = oaB[dt][rq*4+1];
      u[2] = oaB[dt][rq*4+2]; u[3] = oaB[dt][rq*4+3];
      u *= invB;
      *(f32x4*)&opB[dt*32 + rq*8 + hi*4] = u;
    }
}

// ---------------------------------------------------------------------------
extern "C" void kernel_launch(void* const* d_in, const int* in_sizes, int n_in,
                              void* d_out, int out_size, void* d_ws, size_t ws_size,
                              hipStream_t stream){
  (void)in_sizes; (void)n_in; (void)out_size; (void)ws_size;
  const float* x  = (const float*)d_in[0];
  const float* wq = (const float*)d_in[1];
  const float* bq = (const float*)d_in[2];
  const float* wk = (const float*)d_in[3];
  const float* bk = (const float*)d_in[4];
  const float* wv = (const float*)d_in[5];
  const float* bv = (const float*)d_in[6];

  char* ws = (char*)d_ws;
  u16* xb = (u16*)ws;                       // [8192][768]
  u16* wb = (u16*)(ws + 12582912);          // [2304][768]
  u16* Qp = (u16*)(ws + 16121856);          // [48][2048][64]
  u16* Kp = (u16*)(ws + 28704768);          // [48][2048][64]
  u16* Vp = (u16*)(ws + 41287680);          // [48][64][2048]  (V^T)

  convert_all<<<7872, 256, 0, stream>>>(x, wq, wk, wv, xb, wb);
  qkv_gemm<<<1152, 256, 0, stream>>>(xb, wb, bq, bk, bv, Qp, Kp, Vp);
  attn<<<768, 128, 0, stream>>>(Qp, Kp, Vp, (float*)d_out);
}

// Round 7
// 187.896 us; speedup vs baseline: 1.1847x; 1.0788x over previous
//
#include <hip/hip_runtime.h>
#include <cstdint>

#define NSEQ 2048
#define DIM  768
#define NH   12
#define HD   64

typedef __attribute__((ext_vector_type(8)))  short bf16x8;
typedef __attribute__((ext_vector_type(4)))  float f32x4;
typedef __attribute__((ext_vector_type(16))) float f32x16;
typedef __attribute__((ext_vector_type(4)))  int   i32x4;
typedef unsigned short u16;

#define MFMA16(a,b,c) __builtin_amdgcn_mfma_f32_16x16x32_bf16(a,b,c,0,0,0)
#define MFMA32(a,b,c) __builtin_amdgcn_mfma_f32_32x32x16_bf16(a,b,c,0,0,0)

// q' = q * HEAD_DIM^-0.5 * log2(e)  -> attention uses exp2 directly
#define QSCALE 0.1803368801111204f

__device__ __forceinline__ u16 f2bf(float f){
  unsigned u = __builtin_bit_cast(unsigned, f);
  return (u16)((u + 0x7fffu + ((u >> 16) & 1u)) >> 16);   // RNE
}
// pack two floats to bf16x2 in ONE inst (RNE) — T12 recipe (no builtin)
__device__ __forceinline__ int cvtpk(float a, float b){
  int r;
  asm("v_cvt_pk_bf16_f32 %0, %1, %2" : "=v"(r) : "v"(a), "v"(b));
  return r;
}

typedef __attribute__((address_space(1))) void gvoid_t;
typedef __attribute__((address_space(3))) void lvoid_t;
__device__ __forceinline__ void g2l16(const void* g, void* l){
  __builtin_amdgcn_global_load_lds((gvoid_t*)g, (lvoid_t*)l, 16, 0, 0);
}

// ---------------------------------------------------------------------------
// Kernel 0: fp32 -> bf16 conversion of x and the three weight matrices.
// ---------------------------------------------------------------------------
__global__ __launch_bounds__(256) void convert_all(
    const float* __restrict__ x,  const float* __restrict__ wq,
    const float* __restrict__ wk, const float* __restrict__ wv,
    u16* __restrict__ xb, u16* __restrict__ wb){
  int blk = blockIdx.x, tid = threadIdx.x;
  const float* src; u16* dst; long idx;
  if (blk < 6144){ src = x; dst = xb; idx = (long)blk*256 + tid; }
  else {
    int r = blk - 6144; int s = r / 576; r -= s*576;
    src = (s==0) ? wq : (s==1) ? wk : wv;
    dst = wb + (long)s * (768*768);
    idx = (long)r*256 + tid;
  }
  float4 v = ((const float4*)src)[idx];
  ushort4 o;
  o.x = f2bf(v.x); o.y = f2bf(v.y); o.z = f2bf(v.z); o.w = f2bf(v.w);
  ((ushort4*)dst)[idx] = o;
}

// ---------------------------------------------------------------------------
// Kernel 1: fused QKV projection GEMM.
// R6 change: BN 128 -> 96. Old grid was 64x18 = 1152 blocks at 3/CU
// residency (768 concurrent) -> 1 full round + 1 HALF-EMPTY round (~33%
// makespan quantization). New grid 64x24 = 1536 = EXACTLY 2 full rounds.
// Segment math stays exact: 768/96 = 8 tiles per Q/K/V segment.
// Structure otherwise the measured-good R5-session version: 128xBN tile,
// BK=64, g2l16(16B) + XOR-8 swizzle, 16x16x32 MFMA, XCD-local bm cluster.
// Outputs: Q (pre-scaled by 0.125*log2e), K as [bh][n][64]; V^T [bh][64][n].
// ---------------------------------------------------------------------------
__global__ __launch_bounds__(256,3) void qkv_gemm(
    const u16* __restrict__ xb, const u16* __restrict__ wb,
    const float* __restrict__ bq, const float* __restrict__ bk,
    const float* __restrict__ bv,
    u16* __restrict__ Qo, u16* __restrict__ Ko, u16* __restrict__ Vo){
  __shared__ __align__(16) u16 ldsX[128*64];
  __shared__ __align__(16) u16 ldsW[96*64];
  int tid  = threadIdx.x;
  int w    = tid >> 6, lane = tid & 63;
  int xcd  = blockIdx.x & 7, j = blockIdx.x >> 3;     // j in [0,192)
  int bm   = xcd*8 + j/24, bn = j%24;
  int wm   = w >> 1, wn = w & 1;
  int l15  = lane & 15, g = lane >> 4;
  int srow = lane >> 3;
  int scol = ((lane & 7) ^ srow) * 8;

  const u16* xg = xb + (long)bm*128*768;
  const u16* wg = wb + (long)bn*96*768;

  f32x4 acc[4][3] = {};

  for (int k0 = 0; k0 < 768; k0 += 64){
    if (k0) __syncthreads();
    #pragma unroll
    for (int jj = 0; jj < 4; jj++){
      int rr = (w*4 + jj)*8 + srow;
      g2l16(xg + (long)rr*768 + k0 + scol, &ldsX[(w*4 + jj)*512]);
    }
    #pragma unroll
    for (int jj = 0; jj < 3; jj++){
      int rr = (w*3 + jj)*8 + srow;
      g2l16(wg + (long)rr*768 + k0 + scol, &ldsW[(w*3 + jj)*512]);
    }
    __syncthreads();
    #pragma unroll
    for (int ks = 0; ks < 2; ks++){
      bf16x8 af[4], bfr[3];
      #pragma unroll
      for (int im = 0; im < 4; im++){
        int row = wm*64 + im*16 + l15;
        af[im] = *(const bf16x8*)&ldsX[row*64 + (((ks*4 + g) ^ (row & 7))*8)];
      }
      #pragma unroll
      for (int in = 0; in < 3; in++){
        int row = wn*48 + in*16 + l15;
        bfr[in] = *(const bf16x8*)&ldsW[row*64 + (((ks*4 + g) ^ (row & 7))*8)];
      }
      #pragma unroll
      for (int im = 0; im < 4; im++)
        #pragma unroll
        for (int in = 0; in < 3; in++)
          acc[im][in] = MFMA16(af[im], bfr[in], acc[im][in]);
    }
  }

  int seg = bn >> 3;                       // 8 N-tiles of 96 per segment
  const float* bias = (seg==0) ? bq : (seg==1) ? bk : bv;
  #pragma unroll
  for (int in = 0; in < 3; in++){
    int o  = bn*96 + wn*48 + in*16 + l15;
    int oo = o - seg*768;
    int h  = oo >> 6, d = oo & 63;
    float bb = bias[oo];
    #pragma unroll
    for (int im = 0; im < 4; im++){
      int t  = bm*128 + wm*64 + im*16 + g*4;
      int bi = t >> 11, n0 = t & 2047;
      f32x4 a = acc[im][in];
      if (seg == 2){
        ushort4 pk;
        pk.x = f2bf(a[0] + bb); pk.y = f2bf(a[1] + bb);
        pk.z = f2bf(a[2] + bb); pk.w = f2bf(a[3] + bb);
        *(ushort4*)&Vo[((long)(bi*NH + h)*HD + d)*NSEQ + n0] = pk;   // V^T
      } else if (seg == 0){
        #pragma unroll
        for (int r = 0; r < 4; r++)
          Qo[((long)(bi*NH + h)*NSEQ + n0 + r)*HD + d] = f2bf((a[r] + bb)*QSCALE);
      } else {
        #pragma unroll
        for (int r = 0; r < 4; r++)
          Ko[((long)(bi*NH + h)*NSEQ + n0 + r)*HD + d] = f2bf(a[r] + bb);
      }
    }
  }
}

// ---------------------------------------------------------------------------
// Kernel 2: flash attention fwd, 32x32-MFMA pipeline — R2-EXACT (best
// measured: 72.0us). History: R3 ILP-split FAILED correctness; R4 V-from-L2
// gather REGRESSED +58%; R5 2-wave/64-row-tile halved LDS reads+conflicts
// (3.15M, as predicted) but halved occupancy -> 84.6us REGRESSION. The
// 12-wave/CU 32-row config is the measured local optimum; LDS-traffic and
// TLP trade against each other here.
// ---------------------------------------------------------------------------
__global__ __launch_bounds__(256,3) void attn(
    const u16* __restrict__ Q, const u16* __restrict__ K,
    const u16* __restrict__ VT, float* __restrict__ out){
  __shared__ __align__(16) u16 kls[2][64*64];   // [key][d]   8KB per buf
  __shared__ __align__(16) u16 vls[2][64*64];   // [d][key]   8KB per buf
  int tid = threadIdx.x;
  int w   = tid >> 6, lane = tid & 63;
  int xcd = blockIdx.x & 7, j = blockIdx.x >> 3;   // j in [0,96)
  int bh  = xcd*6 + (j >> 4), qc = j & 15;
  int b   = bh / NH, h = bh - b*NH;
  int l31 = lane & 31, hi = lane >> 5;
  int srow = lane >> 3;
  int scol = ((lane & 7) ^ srow) * 8;

  const u16* Qb = Q  + (long)bh*NSEQ*HD;
  const u16* Kb = K  + (long)bh*NSEQ*HD;
  const u16* Vb = VT + (long)bh*HD*NSEQ;

  int r0 = qc*128 + w*32;
  // Q fragments (B-operand of 32x32x16: k=hi*8+j within 16-d window dk)
  bf16x8 qf[4];
  {
    const u16* qrow = Qb + (long)(r0 + l31)*HD;
    #pragma unroll
    for (int dk = 0; dk < 4; dk++)
      qf[dk] = *(const bf16x8*)&qrow[dk*16 + hi*8];
  }

  f32x16 oa[2] = {};            // O^T [d-tile of 32][r=32]
  float ls = 0.f;               // lane-local row sum (q-row = l31)

#define STAGE(c0, bf)                                                         \
  {                                                                           \
    _Pragma("unroll")                                                         \
    for (int jj = 0; jj < 2; jj++){                                           \
      int rr = jj*32 + w*8;                                                   \
      g2l16(Kb + (long)((c0) + rr + srow)*HD + scol,  &kls[bf][rr*64]);       \
      g2l16(Vb + (long)(rr + srow)*NSEQ + (c0) + scol, &vls[bf][rr*64]);      \
    }                                                                         \
  }

  // one 32-key window: Sᵀ = K·Qᵀ -> exp2 -> cvt_pk/permlane exchange -> PV
#define KH(bf, kh)                                                            \
  {                                                                           \
    bf16x8 kf[4];                                                             \
    _Pragma("unroll")                                                         \
    for (int dk = 0; dk < 4; dk++)                                            \
      kf[dk] = *(const bf16x8*)                                               \
        &kls[bf][((kh)*32 + l31)*64 + (((dk*2 + hi) ^ (l31 & 7))*8)];         \
    f32x16 T = {};                                                            \
    __builtin_amdgcn_s_setprio(1);                                            \
    _Pragma("unroll")                                                         \
    for (int dk = 0; dk < 4; dk++)                                            \
      T = MFMA32(kf[dk], qf[dk], T);                                          \
    __builtin_amdgcn_s_setprio(0);                                            \
    int PD[4][2];                                                             \
    _Pragma("unroll")                                                         \
    for (int q = 0; q < 4; q++){                                              \
      float p0 = __builtin_amdgcn_exp2f(T[q*4+0]);                            \
      float p1 = __builtin_amdgcn_exp2f(T[q*4+1]);                            \
      float p2 = __builtin_amdgcn_exp2f(T[q*4+2]);                            \
      float p3 = __builtin_amdgcn_exp2f(T[q*4+3]);                            \
      ls += (p0 + p1) + (p2 + p3);                                            \
      PD[q][0] = cvtpk(p0, p1);                                               \
      PD[q][1] = cvtpk(p2, p3);                                               \
    }                                                                         \
    _Pragma("unroll")                                                         \
    for (int kc = 0; kc < 2; kc++){                                           \
      int a0 = PD[2*kc][0], b0 = PD[2*kc+1][0];                               \
      int a1 = PD[2*kc][1], b1 = PD[2*kc+1][1];                               \
      asm("v_permlane32_swap_b32 %0, %1" : "+v"(a0), "+v"(b0));               \
      asm("v_permlane32_swap_b32 %0, %1" : "+v"(a1), "+v"(b1));               \
      i32x4 pr;                                                               \
      pr[0] = a0; pr[1] = a1; pr[2] = b0; pr[3] = b1;                         \
      bf16x8 pf = __builtin_bit_cast(bf16x8, pr);                             \
      __builtin_amdgcn_s_setprio(1);                                          \
      _Pragma("unroll")                                                       \
      for (int dt = 0; dt < 2; dt++){                                         \
        bf16x8 vf = *(const bf16x8*)                                          \
          &vls[bf][(dt*32 + l31)*64 + ((((kh)*4 + kc*2 + hi) ^ (l31 & 7))*8)];\
        oa[dt] = MFMA32(vf, pf, oa[dt]);                                      \
      }                                                                       \
      __builtin_amdgcn_s_setprio(0);                                          \
    }                                                                         \
  }

  STAGE(0, 0);
  __syncthreads();
  for (int i = 0; i < 32; i++){
    int cb = i & 1, nb = cb ^ 1;
    STAGE(((i+1) & 31)*64, nb);       // wraps to tile 0 on last iter (safe)
    // leading barrier: prev-iter's 4 loads (tile i, buf cb) landed, wave-wide;
    // the 4 just-issued loads (tile i+1, buf nb) stay in flight across it.
    __builtin_amdgcn_sched_barrier(0);
    asm volatile("s_waitcnt vmcnt(4) lgkmcnt(0)" ::: "memory");
    __builtin_amdgcn_sched_barrier(0);
    __builtin_amdgcn_s_barrier();
    KH(cb, 0);
    KH(cb, 1);
    // trailing barrier: all waves finished READING buf cb before iter i+1
    // issues g2l16 writes into it. ds_reads were consumed pre-MFMA (lgkm).
    __builtin_amdgcn_sched_barrier(0);
    asm volatile("s_waitcnt lgkmcnt(0)" ::: "memory");
    __builtin_amdgcn_sched_barrier(0);
    __builtin_amdgcn_s_barrier();
  }
#undef STAGE
#undef KH

  // finish row sum: partner lane holds the complementary keys of row l31
  ls += __shfl_xor(ls, 32);
  float inv = 1.f / ls;

  // O^T: col=r=l31, row=d=(reg&3)+8*(reg>>2)+4*hi (+32*dt) -> float4 stores
  float* op = &out[(long)(b*NSEQ + r0 + l31)*DIM + h*HD];
  #pragma unroll
  for (int dt = 0; dt < 2; dt++)
    #pragma unroll
    for (int rq = 0; rq < 4; rq++){
      f32x4 v;
      v[0] = oa[dt][rq*4+0]; v[1] = oa[dt][rq*4+1];
      v[2] = oa[dt][rq*4+2]; v[3] = oa[dt][rq*4+3];
      v *= inv;
      *(f32x4*)&op[dt*32 + rq*8 + hi*4] = v;
    }
}

// ---------------------------------------------------------------------------
extern "C" void kernel_launch(void* const* d_in, const int* in_sizes, int n_in,
                              void* d_out, int out_size, void* d_ws, size_t ws_size,
                              hipStream_t stream){
  (void)in_sizes; (void)n_in; (void)out_size; (void)ws_size;
  const float* x  = (const float*)d_in[0];
  const float* wq = (const float*)d_in[1];
  const float* bq = (const float*)d_in[2];
  const float* wk = (const float*)d_in[3];
  const float* bk = (const float*)d_in[4];
  const float* wv = (const float*)d_in[5];
  const float* bv = (const float*)d_in[6];

  char* ws = (char*)d_ws;
  u16* xb = (u16*)ws;                       // [8192][768]
  u16* wb = (u16*)(ws + 12582912);          // [2304][768]
  u16* Qp = (u16*)(ws + 16121856);          // [48][2048][64]
  u16* Kp = (u16*)(ws + 28704768);          // [48][2048][64]
  u16* Vp = (u16*)(ws + 41287680);          // [48][64][2048]  (V^T)

  convert_all<<<7872, 256, 0, stream>>>(x, wq, wk, wv, xb, wb);
  qkv_gemm<<<1536, 256, 0, stream>>>(xb, wb, bq, bk, bv, Qp, Kp, Vp);
  attn<<<768, 256, 0, stream>>>(Qp, Kp, Vp, (float*)d_out);
}